// Round 7
// baseline (831.509 us; speedup 1.0000x reference)
//
#include <hip/hip_runtime.h>
#include <hip/hip_fp16.h>
#include <math.h>

#define NN 100000
#define DD 128
#define SCAN_CHUNK 2048

// ---------------- degree histogram + per-edge rank ----------------
__global__ __launch_bounds__(256) void hist_rank_kernel(const int* __restrict__ dst, int E,
                                                        int* __restrict__ deg,
                                                        int* __restrict__ rank) {
    int i = blockIdx.x * 256 + threadIdx.x;
    int e = i * 4;
    if (e + 3 < E) {
        int4 d4 = ((const int4*)dst)[i];
        int4 r4;
        r4.x = atomicAdd(&deg[d4.x], 1);
        r4.y = atomicAdd(&deg[d4.y], 1);
        r4.z = atomicAdd(&deg[d4.z], 1);
        r4.w = atomicAdd(&deg[d4.w], 1);
        ((int4*)rank)[i] = r4;
    } else {
        for (; e < E; ++e) rank[e] = atomicAdd(&deg[dst[e]], 1);
    }
}

// ---------------- scan part 1: per-chunk sums (+ fused dinv) ----------------
__global__ __launch_bounds__(256) void scan1_kernel(const int* __restrict__ deg,
                                                    int* __restrict__ chunkSum,
                                                    float* __restrict__ dinv, int n) {
    __shared__ int lds[256];
    int tid = threadIdx.x;
    int base = blockIdx.x * SCAN_CHUNK + tid * 8;
    int s = 0;
    #pragma unroll
    for (int j = 0; j < 8; ++j) {
        int idx = base + j;
        if (idx < n) {
            int d = deg[idx];
            s += d;
            dinv[idx] = rsqrtf((float)d + 1.0f);
        }
    }
    lds[tid] = s;
    __syncthreads();
    for (int d = 128; d > 0; d >>= 1) {
        if (tid < d) lds[tid] += lds[tid + d];
        __syncthreads();
    }
    if (tid == 0) chunkSum[blockIdx.x] = lds[0];
}

// ---------------- scan part 2: scan chunk sums (1 block) ----------------
__global__ void scan2_kernel(int* __restrict__ chunkSum, int* __restrict__ chunkOff,
                             int nb, int* __restrict__ offsets) {
    __shared__ int lds[512];
    int tid = threadIdx.x;
    if (tid < nb) lds[tid] = chunkSum[tid];
    __syncthreads();
    if (tid == 0) {
        int run = 0;
        for (int i = 0; i < nb; ++i) {
            int v = lds[i];
            lds[i] = run;
            run += v;
        }
        offsets[NN] = run;
    }
    __syncthreads();
    if (tid < nb) chunkOff[tid] = lds[tid];
}

// ---------------- scan part 3: per-chunk exclusive scan ----------------
__global__ __launch_bounds__(256) void scan3_kernel(const int* __restrict__ deg,
                                                    const int* __restrict__ chunkOff,
                                                    int* __restrict__ offsets, int n) {
    __shared__ int lds[256];
    int tid = threadIdx.x;
    int base = blockIdx.x * SCAN_CHUNK + tid * 8;
    int v[8];
    int tsum = 0;
    #pragma unroll
    for (int j = 0; j < 8; ++j) {
        int idx = base + j;
        v[j] = (idx < n) ? deg[idx] : 0;
        tsum += v[j];
    }
    lds[tid] = tsum;
    __syncthreads();
    for (int d = 1; d < 256; d <<= 1) {
        int t = (tid >= d) ? lds[tid - d] : 0;
        __syncthreads();
        lds[tid] += t;
        __syncthreads();
    }
    int excl = lds[tid] - tsum;
    int off0 = chunkOff[blockIdx.x] + excl;
    int run = 0;
    #pragma unroll
    for (int j = 0; j < 8; ++j) {
        int idx = base + j;
        if (idx < n) offsets[idx] = off0 + run;
        run += v[j];
    }
}

// ---------------- CSR fill (atomic-free) ----------------
__global__ __launch_bounds__(256) void fill_kernel(const int* __restrict__ src,
                                                   const int* __restrict__ dst,
                                                   const int* __restrict__ rank, int E,
                                                   const int* __restrict__ offsets,
                                                   int* __restrict__ csr) {
    int i = blockIdx.x * 256 + threadIdx.x;
    int e = i * 4;
    if (e + 3 < E) {
        int4 d4 = ((const int4*)dst)[i];
        int4 s4 = ((const int4*)src)[i];
        int4 r4 = ((const int4*)rank)[i];
        int o0 = offsets[d4.x];
        int o1 = offsets[d4.y];
        int o2 = offsets[d4.z];
        int o3 = offsets[d4.w];
        csr[o0 + r4.x] = s4.x;
        csr[o1 + r4.y] = s4.y;
        csr[o2 + r4.z] = s4.z;
        csr[o3 + r4.w] = s4.w;
    } else {
        for (; e < E; ++e) csr[offsets[dst[e]] + rank[e]] = src[e];
    }
}

// ---------------- GEMM + src-norm fuse: g = fp16((X @ W) * dinv[row]) ----------------
__global__ __launch_bounds__(256, 2) void gemm_norm_kernel(
    const float* __restrict__ X, const float* __restrict__ W,
    const float* __restrict__ dinv, __half* __restrict__ G)
{
    __shared__ float ws[128 * 128];     // 64 KB

    const int tid  = threadIdx.x;
    const int base = blockIdx.x * 128;

    {
        const float4* W4 = (const float4*)W;
        float4* S4 = (float4*)ws;
        #pragma unroll
        for (int it = 0; it < 16; ++it) S4[tid + it * 256] = W4[tid + it * 256];
    }
    __syncthreads();

    const int cg = tid & 7;        // cols cg*4 + s*32
    const int rp = tid >> 3;       // 0..31
    const int r0 = rp * 4;

    const float4* xp[4];
    int rows[4];
    #pragma unroll
    for (int r = 0; r < 4; ++r) {
        int row = base + r0 + r;
        rows[r] = row;
        int rc = (row < NN) ? row : (NN - 1);
        xp[r] = (const float4*)&X[(size_t)rc * DD];
    }

    float acc[4][4][4];
    #pragma unroll
    for (int r = 0; r < 4; ++r)
        #pragma unroll
        for (int s = 0; s < 4; ++s)
            #pragma unroll
            for (int c = 0; c < 4; ++c) acc[r][s][c] = 0.f;

    float4 cur[4], nxt[4];
    #pragma unroll
    for (int r = 0; r < 4; ++r) cur[r] = xp[r][0];

    for (int kc = 0; kc < 32; ++kc) {
        if (kc + 1 < 32) {
            #pragma unroll
            for (int r = 0; r < 4; ++r) nxt[r] = xp[r][kc + 1];
        }
        const float* wb = &ws[kc * 4 * 128];
        #pragma unroll
        for (int kk = 0; kk < 4; ++kk) {
            float xk0 = ((const float*)&cur[0])[kk];
            float xk1 = ((const float*)&cur[1])[kk];
            float xk2 = ((const float*)&cur[2])[kk];
            float xk3 = ((const float*)&cur[3])[kk];
            #pragma unroll
            for (int s = 0; s < 4; ++s) {
                const float4 wv = *(const float4*)&wb[kk * 128 + cg * 4 + s * 32];
                acc[0][s][0] += xk0 * wv.x; acc[0][s][1] += xk0 * wv.y;
                acc[0][s][2] += xk0 * wv.z; acc[0][s][3] += xk0 * wv.w;
                acc[1][s][0] += xk1 * wv.x; acc[1][s][1] += xk1 * wv.y;
                acc[1][s][2] += xk1 * wv.z; acc[1][s][3] += xk1 * wv.w;
                acc[2][s][0] += xk2 * wv.x; acc[2][s][1] += xk2 * wv.y;
                acc[2][s][2] += xk2 * wv.z; acc[2][s][3] += xk2 * wv.w;
                acc[3][s][0] += xk3 * wv.x; acc[3][s][1] += xk3 * wv.y;
                acc[3][s][2] += xk3 * wv.z; acc[3][s][3] += xk3 * wv.w;
            }
        }
        #pragma unroll
        for (int r = 0; r < 4; ++r) cur[r] = nxt[r];
    }

    #pragma unroll
    for (int r = 0; r < 4; ++r) {
        if (rows[r] < NN) {
            float di = dinv[rows[r]];
            #pragma unroll
            for (int s = 0; s < 4; ++s) {
                __half2 h01 = __floats2half2_rn(acc[r][s][0] * di, acc[r][s][1] * di);
                __half2 h23 = __floats2half2_rn(acc[r][s][2] * di, acc[r][s][3] * di);
                __half2* gp = (__half2*)&G[rows[r] * DD + cg * 4 + s * 32];
                gp[0] = h01;
                gp[1] = h23;
            }
        }
    }
}

// ---------------- gather-aggregate + bias + relu (feature-quartered) ----------------
// Quarter q = blockIdx&3 (XCD round-robin pins each XCD to one 6.4MB quarter of g).
// One node per wave; lane = subgroup(0..3) x colpair(0..15): 4 edges / gather instr,
// 64B (one line) per edge per quarter. __shfl_xor reduce across subgroups.
__global__ __launch_bounds__(256) void agg_kernel(
    const __half* __restrict__ g, const float* __restrict__ dinv,
    const int* __restrict__ off, const int* __restrict__ csr,
    const float* __restrict__ bias, float* __restrict__ out)
{
    const int tid  = threadIdx.x;
    const int wid  = tid >> 6;        // 0..3
    const int lane = tid & 63;
    const int q    = blockIdx.x & 3;  // feature quarter
    const int sub  = lane >> 4;       // edge subgroup 0..3
    const int cl   = lane & 15;       // col-pair within quarter

    const __half2* __restrict__ g2 = (const __half2*)g;   // row stride 64 (half2)
    const int colbase = q * 16 + cl;

    for (int n = (int)(blockIdx.x >> 2) * 4 + wid; n < NN; n += 8192) {
        int start = off[n], end = off[n + 1];
        float2 acc = make_float2(0.f, 0.f);
        if (sub == 0) {                       // self-loop (count once)
            acc = __half22float2(g2[n * 64 + colbase]);
        }
        int e = start;
        int end4 = start + ((end - start) & ~3);
        for (; e < end4; e += 4) {
            int s = csr[e + sub];
            float2 v = __half22float2(g2[s * 64 + colbase]);
            acc.x += v.x; acc.y += v.y;
        }
        int rem = end - e;
        if (rem > 0) {
            int ee = e + ((sub < rem) ? sub : 0);
            int s = csr[ee];
            float2 v = __half22float2(g2[s * 64 + colbase]);
            if (sub < rem) { acc.x += v.x; acc.y += v.y; }
        }
        // reduce across the 4 subgroups (lanes l, l+16, l+32, l+48)
        acc.x += __shfl_xor(acc.x, 16, 64);
        acc.y += __shfl_xor(acc.y, 16, 64);
        acc.x += __shfl_xor(acc.x, 32, 64);
        acc.y += __shfl_xor(acc.y, 32, 64);
        if (sub == 0) {
            float di = dinv[n];
            float2 bb = ((const float2*)bias)[colbase];
            float2 o;
            o.x = fmaxf(fmaf(acc.x, di, bb.x), 0.f);
            o.y = fmaxf(fmaf(acc.y, di, bb.y), 0.f);
            ((float2*)out)[n * 64 + colbase] = o;
        }
    }
}

extern "C" void kernel_launch(void* const* d_in, const int* in_sizes, int n_in,
                              void* d_out, int out_size, void* d_ws, size_t ws_size,
                              hipStream_t stream)
{
    const float* x  = (const float*)d_in[0];
    const float* W1 = (const float*)d_in[1];
    const float* b1 = (const float*)d_in[2];
    const float* W2 = (const float*)d_in[3];
    const float* b2 = (const float*)d_in[4];
    const float* W3 = (const float*)d_in[5];
    const float* b3 = (const float*)d_in[6];
    const int*   ei = (const int*)d_in[7];

    const int E = in_sizes[7] / 2;          // 1,600,000
    const int* src = ei;
    const int* dst = ei + E;

    float* out = (float*)d_out;

    // ---- workspace layout ----
    char* wsb = (char*)d_ws;
    size_t p = 0;
    int* deg      = (int*)(wsb + p); p += ((size_t)NN * 4 + 1023) & ~1023ull;
    int* offsets  = (int*)(wsb + p); p += ((size_t)(NN + 1) * 4 + 1023) & ~1023ull;
    int* chunkSum = (int*)(wsb + p); p += 4096;
    int* chunkOff = (int*)(wsb + p); p += 4096;
    int* csr      = (int*)(wsb + p); p += ((size_t)E * 4 + 1023) & ~1023ull;
    int* rank     = (int*)(wsb + p); p += ((size_t)E * 4 + 1023) & ~1023ull;
    float* dinv   = (float*)(wsb + p); p += ((size_t)NN * 4 + 1023) & ~1023ull;
    __half* g     = (__half*)(wsb + p); p += (size_t)NN * DD * 2;

    const int NB = (NN + SCAN_CHUNK - 1) / SCAN_CHUNK;   // 49

    // ---- CSR build + dinv ----
    hipMemsetAsync(deg, 0, (size_t)NN * 4, stream);
    hist_rank_kernel<<<(E / 4 + 256) / 256 + 1, 256, 0, stream>>>(dst, E, deg, rank);
    scan1_kernel<<<NB, 256, 0, stream>>>(deg, chunkSum, dinv, NN);
    scan2_kernel<<<1, 512, 0, stream>>>(chunkSum, chunkOff, NB, offsets);
    scan3_kernel<<<NB, 256, 0, stream>>>(deg, chunkOff, offsets, NN);
    fill_kernel<<<(E / 4 + 256) / 256 + 1, 256, 0, stream>>>(src, dst, rank, E, offsets, csr);

    const int gemm_grid = (NN + 127) / 128;   // 782
    const int agg_grid  = 8192;               // 4 quarters x 2048 node-blocks

    // ---- layer 1 ----
    gemm_norm_kernel<<<gemm_grid, 256, 0, stream>>>(x, W1, dinv, g);
    agg_kernel<<<agg_grid, 256, 0, stream>>>(g, dinv, offsets, csr, b1, out);
    // ---- layer 2 ----
    gemm_norm_kernel<<<gemm_grid, 256, 0, stream>>>(out, W2, dinv, g);
    agg_kernel<<<agg_grid, 256, 0, stream>>>(g, dinv, offsets, csr, b2, out);
    // ---- layer 3 ----
    gemm_norm_kernel<<<gemm_grid, 256, 0, stream>>>(out, W3, dinv, g);
    agg_kernel<<<agg_grid, 256, 0, stream>>>(g, dinv, offsets, csr, b3, out);
}

// Round 8
// 413.031 us; speedup vs baseline: 2.0132x; 2.0132x over previous
//
#include <hip/hip_runtime.h>
#include <hip/hip_fp16.h>
#include <math.h>

#define NN 100000
#define DD 128
#define SCAN_CHUNK 2048

typedef short short8 __attribute__((ext_vector_type(8)));
typedef float f32x4 __attribute__((ext_vector_type(4)));

// ---------------- degree histogram + per-edge rank ----------------
__global__ __launch_bounds__(256) void hist_rank_kernel(const int* __restrict__ dst, int E,
                                                        int* __restrict__ deg,
                                                        int* __restrict__ rank) {
    int i = blockIdx.x * 256 + threadIdx.x;
    int e = i * 4;
    if (e + 3 < E) {
        int4 d4 = ((const int4*)dst)[i];
        int4 r4;
        r4.x = atomicAdd(&deg[d4.x], 1);
        r4.y = atomicAdd(&deg[d4.y], 1);
        r4.z = atomicAdd(&deg[d4.z], 1);
        r4.w = atomicAdd(&deg[d4.w], 1);
        ((int4*)rank)[i] = r4;
    } else {
        for (; e < E; ++e) rank[e] = atomicAdd(&deg[dst[e]], 1);
    }
}

// ---------------- scan part 1: per-chunk sums (+ fused dinv) ----------------
__global__ __launch_bounds__(256) void scan1_kernel(const int* __restrict__ deg,
                                                    int* __restrict__ chunkSum,
                                                    float* __restrict__ dinv, int n) {
    __shared__ int lds[256];
    int tid = threadIdx.x;
    int base = blockIdx.x * SCAN_CHUNK + tid * 8;
    int s = 0;
    #pragma unroll
    for (int j = 0; j < 8; ++j) {
        int idx = base + j;
        if (idx < n) {
            int d = deg[idx];
            s += d;
            dinv[idx] = rsqrtf((float)d + 1.0f);
        }
    }
    lds[tid] = s;
    __syncthreads();
    for (int d = 128; d > 0; d >>= 1) {
        if (tid < d) lds[tid] += lds[tid + d];
        __syncthreads();
    }
    if (tid == 0) chunkSum[blockIdx.x] = lds[0];
}

// ---------------- scan part 2 ----------------
__global__ void scan2_kernel(int* __restrict__ chunkSum, int* __restrict__ chunkOff,
                             int nb, int* __restrict__ offsets) {
    __shared__ int lds[512];
    int tid = threadIdx.x;
    if (tid < nb) lds[tid] = chunkSum[tid];
    __syncthreads();
    if (tid == 0) {
        int run = 0;
        for (int i = 0; i < nb; ++i) {
            int v = lds[i];
            lds[i] = run;
            run += v;
        }
        offsets[NN] = run;
    }
    __syncthreads();
    if (tid < nb) chunkOff[tid] = lds[tid];
}

// ---------------- scan part 3 ----------------
__global__ __launch_bounds__(256) void scan3_kernel(const int* __restrict__ deg,
                                                    const int* __restrict__ chunkOff,
                                                    int* __restrict__ offsets, int n) {
    __shared__ int lds[256];
    int tid = threadIdx.x;
    int base = blockIdx.x * SCAN_CHUNK + tid * 8;
    int v[8];
    int tsum = 0;
    #pragma unroll
    for (int j = 0; j < 8; ++j) {
        int idx = base + j;
        v[j] = (idx < n) ? deg[idx] : 0;
        tsum += v[j];
    }
    lds[tid] = tsum;
    __syncthreads();
    for (int d = 1; d < 256; d <<= 1) {
        int t = (tid >= d) ? lds[tid - d] : 0;
        __syncthreads();
        lds[tid] += t;
        __syncthreads();
    }
    int excl = lds[tid] - tsum;
    int off0 = chunkOff[blockIdx.x] + excl;
    int run = 0;
    #pragma unroll
    for (int j = 0; j < 8; ++j) {
        int idx = base + j;
        if (idx < n) offsets[idx] = off0 + run;
        run += v[j];
    }
}

// ---------------- CSR fill (atomic-free) ----------------
__global__ __launch_bounds__(256) void fill_kernel(const int* __restrict__ src,
                                                   const int* __restrict__ dst,
                                                   const int* __restrict__ rank, int E,
                                                   const int* __restrict__ offsets,
                                                   int* __restrict__ csr) {
    int i = blockIdx.x * 256 + threadIdx.x;
    int e = i * 4;
    if (e + 3 < E) {
        int4 d4 = ((const int4*)dst)[i];
        int4 s4 = ((const int4*)src)[i];
        int4 r4 = ((const int4*)rank)[i];
        int o0 = offsets[d4.x];
        int o1 = offsets[d4.y];
        int o2 = offsets[d4.z];
        int o3 = offsets[d4.w];
        csr[o0 + r4.x] = s4.x;
        csr[o1 + r4.y] = s4.y;
        csr[o2 + r4.z] = s4.z;
        csr[o3 + r4.w] = s4.w;
    } else {
        for (; e < E; ++e) csr[offsets[dst[e]] + rank[e]] = src[e];
    }
}

// ---------------- helpers: fp32 -> bf16 split ----------------
__device__ __forceinline__ unsigned short f2bf(float f) {
    unsigned int u = __float_as_uint(f);
    unsigned int r = u + 0x7FFFu + ((u >> 16) & 1u);
    return (unsigned short)(r >> 16);
}

__device__ __forceinline__ void split8(const float* v, short8& hi, short8& lo) {
    #pragma unroll
    for (int j = 0; j < 8; ++j) {
        float f = v[j];
        unsigned short h = f2bf(f);
        float fl = f - __uint_as_float(((unsigned int)h) << 16);
        hi[j] = (short)h;
        lo[j] = (short)f2bf(fl);
    }
}

// ---------------- MFMA GEMM + src-norm fuse: g = fp16((X @ W) * dinv[row]) ----------------
// 128x128 tile, 4 waves (wave w: rows w*32..w*32+31), K=128.
// Markidis 2-term bf16 split: acc = Xh*Wh + Xl*Wh + Xh*Wl  (fp32 accum).
// W pre-split into fragment-ordered LDS: whf/wlf[(cf*4+ks)*64 + lane] = 8 bf16.
// mfma_f32_16x16x32_bf16: A lane: m=l&15, k=(l>>4)*8+j ; B lane: n=l&15, same k.
// C/D: n=lane&15, m=(lane>>4)*4+reg  [m89 verified].
__global__ __launch_bounds__(256, 2) void gemm_norm_kernel(
    const float* __restrict__ X, const float* __restrict__ W,
    const float* __restrict__ dinv, __half* __restrict__ G)
{
    __shared__ uint4 whf[2048];   // 32 KB
    __shared__ uint4 wlf[2048];   // 32 KB

    const int tid  = threadIdx.x;
    const int base = blockIdx.x * 128;
    const int lane = tid & 63;
    const int wv   = tid >> 6;        // wave 0..3
    const int kg   = lane >> 4;       // k-group 0..3
    const int mcol = lane & 15;       // A-row / D-col

    // ---- stage W into fragment-ordered LDS (hi/lo split) ----
    #pragma unroll
    for (int p = 0; p < 8; ++p) {
        int i = tid + p * 256;            // 0..2047
        int lane_e = i & 63;
        int ks = (i >> 6) & 3;
        int cf = i >> 8;
        int colb = cf * 16 + (lane_e & 15);
        int rowb = ks * 32 + (lane_e >> 4) * 8;
        float wvv[8];
        #pragma unroll
        for (int j = 0; j < 8; ++j) wvv[j] = W[(rowb + j) * DD + colb];
        short8 h, l;
        split8(wvv, h, l);
        union { short8 s; uint4 u; } ch, cl;
        ch.s = h; cl.s = l;
        whf[i] = ch.u;
        wlf[i] = cl.u;
    }

    // ---- load A fragments (X) straight from global, split to bf16 hi/lo ----
    short8 ah[2][4], al[2][4];
    #pragma unroll
    for (int rf = 0; rf < 2; ++rf) {
        int arow = base + wv * 32 + rf * 16 + mcol;
        if (arow >= NN) arow = NN - 1;                 // clamp (stores guarded)
        const float* xr = X + (size_t)arow * DD;
        #pragma unroll
        for (int ks = 0; ks < 4; ++ks) {
            int k0 = ks * 32 + kg * 8;
            float av[8];
            *(float4*)&av[0] = *(const float4*)&xr[k0];
            *(float4*)&av[4] = *(const float4*)&xr[k0 + 4];
            split8(av, ah[rf][ks], al[rf][ks]);
        }
    }
    __syncthreads();

    // ---- main loop over 8 column-fragments ----
    #pragma unroll 1
    for (int cf = 0; cf < 8; ++cf) {
        f32x4 acc0 = {0.f, 0.f, 0.f, 0.f};
        f32x4 acc1 = {0.f, 0.f, 0.f, 0.f};
        #pragma unroll
        for (int ks = 0; ks < 4; ++ks) {
            union { uint4 u; short8 s; } bh, bl;
            bh.u = whf[(cf * 4 + ks) * 64 + lane];
            bl.u = wlf[(cf * 4 + ks) * 64 + lane];
            acc0 = __builtin_amdgcn_mfma_f32_16x16x32_bf16(ah[0][ks], bh.s, acc0, 0, 0, 0);
            acc0 = __builtin_amdgcn_mfma_f32_16x16x32_bf16(al[0][ks], bh.s, acc0, 0, 0, 0);
            acc0 = __builtin_amdgcn_mfma_f32_16x16x32_bf16(ah[0][ks], bl.s, acc0, 0, 0, 0);
            acc1 = __builtin_amdgcn_mfma_f32_16x16x32_bf16(ah[1][ks], bh.s, acc1, 0, 0, 0);
            acc1 = __builtin_amdgcn_mfma_f32_16x16x32_bf16(al[1][ks], bh.s, acc1, 0, 0, 0);
            acc1 = __builtin_amdgcn_mfma_f32_16x16x32_bf16(ah[1][ks], bl.s, acc1, 0, 0, 0);
        }
        // ---- epilogue: scale by dinv[row], store fp16 ----
        #pragma unroll
        for (int rf = 0; rf < 2; ++rf) {
            const f32x4 acc = rf ? acc1 : acc0;
            int row0 = base + wv * 32 + rf * 16 + kg * 4;   // m = kg*4 + reg
            if (row0 < NN) {                                 // row0%4==0 -> all 4 valid
                float dv[4];
                *(float4*)dv = *(const float4*)&dinv[row0];
                #pragma unroll
                for (int j = 0; j < 4; ++j) {
                    G[(size_t)(row0 + j) * DD + cf * 16 + mcol] =
                        __float2half(acc[j] * dv[j]);
                }
            }
        }
    }
}

// ---------------- gather-aggregate + bias + relu (round-6 version) ----------------
__global__ __launch_bounds__(256) void agg_kernel(
    const __half* __restrict__ g, const float* __restrict__ dinv,
    const int* __restrict__ off, const int* __restrict__ csr,
    const float* __restrict__ bias, float* __restrict__ out)
{
    int node = (blockIdx.x * 256 + threadIdx.x) >> 6;
    if (node >= NN) return;
    int lane = threadIdx.x & 63;
    const __half2* __restrict__ g2 = (const __half2*)g;

    float2 acc0 = __half22float2(g2[node * 64 + lane]);   // self-loop message
    float2 acc1 = make_float2(0.f, 0.f);

    int e = off[node], end = off[node + 1];
    int cnt = end - e;
    int e8end = e + (cnt & ~7);

    if (e < e8end) {
        int idx[8];
        #pragma unroll
        for (int j = 0; j < 8; ++j) idx[j] = csr[e + j];
        e += 8;
        for (; e < e8end; e += 8) {
            int nidx[8];
            #pragma unroll
            for (int j = 0; j < 8; ++j) nidx[j] = csr[e + j];
            #pragma unroll
            for (int j = 0; j < 8; j += 2) {
                float2 v0 = __half22float2(g2[idx[j] * 64 + lane]);
                float2 v1 = __half22float2(g2[idx[j + 1] * 64 + lane]);
                acc0.x += v0.x; acc0.y += v0.y;
                acc1.x += v1.x; acc1.y += v1.y;
            }
            #pragma unroll
            for (int j = 0; j < 8; ++j) idx[j] = nidx[j];
        }
        #pragma unroll
        for (int j = 0; j < 8; j += 2) {
            float2 v0 = __half22float2(g2[idx[j] * 64 + lane]);
            float2 v1 = __half22float2(g2[idx[j + 1] * 64 + lane]);
            acc0.x += v0.x; acc0.y += v0.y;
            acc1.x += v1.x; acc1.y += v1.y;
        }
    }
    for (; e < end; ++e) {
        float2 v = __half22float2(g2[csr[e] * 64 + lane]);
        acc0.x += v.x; acc0.y += v.y;
    }

    float di = dinv[node];
    float2 bb = ((const float2*)bias)[lane];
    float2 o;
    o.x = fmaxf(fmaf(acc0.x + acc1.x, di, bb.x), 0.f);
    o.y = fmaxf(fmaf(acc0.y + acc1.y, di, bb.y), 0.f);
    ((float2*)out)[node * 64 + lane] = o;
}

extern "C" void kernel_launch(void* const* d_in, const int* in_sizes, int n_in,
                              void* d_out, int out_size, void* d_ws, size_t ws_size,
                              hipStream_t stream)
{
    const float* x  = (const float*)d_in[0];
    const float* W1 = (const float*)d_in[1];
    const float* b1 = (const float*)d_in[2];
    const float* W2 = (const float*)d_in[3];
    const float* b2 = (const float*)d_in[4];
    const float* W3 = (const float*)d_in[5];
    const float* b3 = (const float*)d_in[6];
    const int*   ei = (const int*)d_in[7];

    const int E = in_sizes[7] / 2;          // 1,600,000
    const int* src = ei;
    const int* dst = ei + E;

    float* out = (float*)d_out;

    // ---- workspace layout ----
    char* wsb = (char*)d_ws;
    size_t p = 0;
    int* deg      = (int*)(wsb + p); p += ((size_t)NN * 4 + 1023) & ~1023ull;
    int* offsets  = (int*)(wsb + p); p += ((size_t)(NN + 1) * 4 + 1023) & ~1023ull;
    int* chunkSum = (int*)(wsb + p); p += 4096;
    int* chunkOff = (int*)(wsb + p); p += 4096;
    int* csr      = (int*)(wsb + p); p += ((size_t)E * 4 + 1023) & ~1023ull;
    int* rank     = (int*)(wsb + p); p += ((size_t)E * 4 + 1023) & ~1023ull;
    float* dinv   = (float*)(wsb + p); p += ((size_t)NN * 4 + 1023) & ~1023ull;
    __half* g     = (__half*)(wsb + p); p += (size_t)NN * DD * 2;

    const int NB = (NN + SCAN_CHUNK - 1) / SCAN_CHUNK;   // 49

    // ---- CSR build + dinv ----
    hipMemsetAsync(deg, 0, (size_t)NN * 4, stream);
    hist_rank_kernel<<<(E / 4 + 256) / 256 + 1, 256, 0, stream>>>(dst, E, deg, rank);
    scan1_kernel<<<NB, 256, 0, stream>>>(deg, chunkSum, dinv, NN);
    scan2_kernel<<<1, 512, 0, stream>>>(chunkSum, chunkOff, NB, offsets);
    scan3_kernel<<<NB, 256, 0, stream>>>(deg, chunkOff, offsets, NN);
    fill_kernel<<<(E / 4 + 256) / 256 + 1, 256, 0, stream>>>(src, dst, rank, E, offsets, csr);

    const int gemm_grid = (NN + 127) / 128;               // 782
    const int agg_grid  = ((size_t)NN * 64 + 255) / 256;  // 25000

    // ---- layer 1 ----
    gemm_norm_kernel<<<gemm_grid, 256, 0, stream>>>(x, W1, dinv, g);
    agg_kernel<<<agg_grid, 256, 0, stream>>>(g, dinv, offsets, csr, b1, out);
    // ---- layer 2 ----
    gemm_norm_kernel<<<gemm_grid, 256, 0, stream>>>(out, W2, dinv, g);
    agg_kernel<<<agg_grid, 256, 0, stream>>>(g, dinv, offsets, csr, b2, out);
    // ---- layer 3 ----
    gemm_norm_kernel<<<gemm_grid, 256, 0, stream>>>(out, W3, dinv, g);
    agg_kernel<<<agg_grid, 256, 0, stream>>>(g, dinv, offsets, csr, b3, out);
}